// Round 15
// baseline (424.336 us; speedup 1.0000x reference)
//
#include <hip/hip_runtime.h>

#define B_ 4
#define N_ 4096
#define K_ 16
#define C_ 128
#define NQ (B_*N_)            // 16384 query points
#define COLS_TOT (NQ*K_)      // 262144 (b,n,k) columns
#define CNT_F 262144.0f
#define EPS_ 1e-5f

typedef __attribute__((ext_vector_type(8))) short short8;
typedef __attribute__((ext_vector_type(4))) float f4;
typedef __attribute__((ext_vector_type(4))) int i4;

__device__ __forceinline__ unsigned short f2bf(float f){
  unsigned u = __builtin_bit_cast(unsigned, f);
  u = u + 0x7fffu + ((u >> 16) & 1u);     // RNE
  return (unsigned short)(u >> 16);
}
__device__ __forceinline__ float bf2f(unsigned short h){
  return __builtin_bit_cast(float, ((unsigned)h) << 16);
}
__device__ __forceinline__ int swzc(int c){ return c ^ ((c >> 3) & 7); }

// ---------------------------------------------------------------------------
// Weight conversion: W0b=W0[:,3:131], W0c=W0[:,131:259], W1, W2 -> bf16
// ---------------------------------------------------------------------------
__global__ __launch_bounds__(256) void wconv(
    const float* __restrict__ W0, const float* __restrict__ W1, const float* __restrict__ W2,
    unsigned short* __restrict__ W0b, unsigned short* __restrict__ W0c,
    unsigned short* __restrict__ W1b, unsigned short* __restrict__ W2b)
{
  int i = blockIdx.x * 256 + threadIdx.x;
  int sel = i >> 14, r = i & 16383;
  int o = r >> 7, c = r & 127;
  float v; unsigned short* dst;
  if (sel == 0)      { v = W0[o*259 + 3   + c]; dst = W0b; }
  else if (sel == 1) { v = W0[o*259 + 131 + c]; dst = W0c; }
  else if (sel == 2) { v = W1[o*128 + c];       dst = W1b; }
  else               { v = W2[o*128 + c];       dst = W2b; }
  dst[r] = f2bf(v);
}

// ---------------------------------------------------------------------------
// KNN stage 1 — r12 version (121us, VALUBusy 97%), TRANSPOSED output layout:
// kdout/kiout[entry][q] so the merge reads coalesced.
// sgemm-mirror fp32 arithmetic (VERIFIED r10).
// ---------------------------------------------------------------------------
__global__ __launch_bounds__(256) void knn_chunk(
    const float* __restrict__ pos1, const float* __restrict__ pos2,
    float* __restrict__ kdout, int* __restrict__ kiout)
{
  __shared__ __align__(16) float pts[256*4];    // 4 KB
  int bx = blockIdx.x;
  int b = bx >> 8, rest = bx & 255, ngrp = rest >> 4, chunk = rest & 15;
  int t = threadIdx.x;
  int m0 = chunk * 256;
  const float* p2 = pos2 + (size_t)b*3*N_;
  {
    int m = m0 + t;
    float x = p2[m], y = p2[N_ + m], z = p2[2*N_ + m];
    float sq = __fadd_rn(__fadd_rn(__fmul_rn(x,x), __fmul_rn(y,y)), __fmul_rn(z,z));
    f4 v; v.x = x; v.y = y; v.z = z; v.w = sq;
    *(f4*)(pts + t*4) = v;
  }
  __syncthreads();

  int n = ngrp*256 + t;
  const float* p1 = pos1 + (size_t)b*3*N_;
  float qx = p1[n], qy = p1[N_ + n], qz = p1[2*N_ + n];
  float qs = __fadd_rn(__fadd_rn(__fmul_rn(qx,qx), __fmul_rn(qy,qy)), __fmul_rn(qz,qz));

  float kd[16]; int ki[16];
  #pragma unroll
  for (int j = 0; j < 16; ++j){ kd[j] = 3.4e38f; ki[j] = 0; }
  float worst = 3.4e38f;
  float pd = 0.f; int pi = 0; bool pv = false;

  auto flush = [&](){
    float d0 = pv ? pd : 3.4e38f; int i0 = pi;
    #pragma unroll
    for (int j = 15; j >= 1; --j){
      bool cj = kd[j] > d0, cm = kd[j-1] > d0;
      kd[j] = cj ? (cm ? kd[j-1] : d0) : kd[j];
      ki[j] = cj ? (cm ? ki[j-1] : i0) : ki[j];
    }
    { bool c0 = kd[0] > d0; kd[0] = c0 ? d0 : kd[0]; ki[0] = c0 ? i0 : ki[0]; }
    worst = kd[15]; pv = false;
  };

  for (int bt = 0; bt < 32; ++bt){
    #pragma unroll
    for (int e = 0; e < 8; ++e){
      int it = bt*8 + e;
      f4 c = *(const f4*)(pts + it*4);
      float dot = __builtin_fmaf(qz, c.z,
                    __builtin_fmaf(qy, c.y, __fmul_rn(qx, c.x)));
      float d = __fsub_rn(__fadd_rn(qs, c.w), __fmul_rn(2.0f, dot));
      bool pass = d < worst;
      if (__any(pass && pv)) flush();     // overflow flush
      if (pass){ pd = d; pi = m0 + it; pv = true; }
    }
    if (__any(pv)) flush();
  }
  if (__any(pv)) flush();

  int q = b*N_ + n;                       // consecutive per lane -> coalesced
  #pragma unroll
  for (int j = 0; j < 16; ++j){
    kdout[(size_t)(chunk*16 + j)*NQ + q] = kd[j];
    kiout[(size_t)(chunk*16 + j)*NQ + q] = ki[j];
  }
}

// KNN stage 2: merge 16 sorted 16-lists. Transposed layout -> coalesced
// scalar loads; each list prefetched to registers (ILP); ascending-list
// early-exit. Entry order (l,j) == index order; strict < (stable low-index).
__global__ __launch_bounds__(256) void knn_merge(
    const float* __restrict__ kdin, const int* __restrict__ kiin, int* __restrict__ idxout)
{
  int q = blockIdx.x*256 + threadIdx.x;
  float kd[16]; int ki[16];
  #pragma unroll
  for (int j = 0; j < 16; ++j){ kd[j] = 3.4e38f; ki[j] = 0; }
  #pragma unroll 1
  for (int l = 0; l < 16; ++l){
    float dv[16]; int iv[16];
    #pragma unroll
    for (int j = 0; j < 16; ++j){
      dv[j] = kdin[(size_t)(l*16 + j)*NQ + q];
      iv[j] = kiin[(size_t)(l*16 + j)*NQ + q];
    }
    bool dead = false;
    #pragma unroll
    for (int j = 0; j < 16; ++j){
      bool ins = !dead && (kd[15] > dv[j]);
      dead = !ins;                       // ascending list: first fail kills rest
      if (__any(ins)){
        if (ins){
          float d0 = dv[j]; int i0 = iv[j];
          #pragma unroll
          for (int jj = 15; jj >= 1; --jj){
            bool cj = kd[jj] > d0, cm = kd[jj-1] > d0;
            kd[jj] = cj ? (cm ? kd[jj-1] : d0) : kd[jj];
            ki[jj] = cj ? (cm ? ki[jj-1] : i0) : ki[jj];
          }
          bool c0 = kd[0] > d0; kd[0] = c0 ? d0 : kd[0]; ki[0] = c0 ? i0 : ki[0];
        }
      }
    }
  }
  #pragma unroll
  for (int j = 0; j < 4; ++j){
    i4 v; v.x = ki[j*4]; v.y = ki[j*4+1]; v.z = ki[j*4+2]; v.w = ki[j*4+3];
    *(i4*)(idxout + (size_t)q*16 + j*4) = v;
  }
}

// ---------------------------------------------------------------------------
// P1: F2t[b][m][o] = (W0b @ feature2), PREt[b][n][o] = (W0c @ feature1)
// Staging rewritten for coalesced global loads (lanes read consecutive m).
// ---------------------------------------------------------------------------
__global__ __launch_bounds__(256) void p1_gemm(
    const float* __restrict__ feat2, const float* __restrict__ feat1,
    const unsigned short* __restrict__ W0b, const unsigned short* __restrict__ W0c,
    float* __restrict__ F2t, float* __restrict__ PREt)
{
  __shared__ __align__(16) unsigned short X[16*128*8];  // 32KB
  int bid = blockIdx.x;
  int sel = bid >> 7;
  const float* src = sel ? feat1 : feat2;
  const unsigned short* W = sel ? W0c : W0b;
  float* dst = sel ? PREt : F2t;
  int c0 = (bid & 127) * 128;
  int b = c0 >> 12, mm0 = c0 & 4095;
  int t = threadIdx.x;
  {
    int colt = t & 127, chh = t >> 7;      // 2 channels per iteration
    #pragma unroll 4
    for (int it = 0; it < 64; ++it){
      int ch = it*2 + chh;
      float v = src[((size_t)b*C_ + ch)*N_ + mm0 + colt];
      X[(ch >> 3)*1024 + swzc(colt)*8 + (ch & 7)] = f2bf(v);
    }
  }
  int lane = t & 63, w = t >> 6;
  int or0 = (w >> 1)*64, c0w = (w & 1)*64;
  int lr = lane & 15, lg = lane >> 4;
  short8 af[4][4];
  #pragma unroll
  for (int ks = 0; ks < 4; ++ks)
    #pragma unroll
    for (int i = 0; i < 4; ++i)
      af[ks][i] = *(const short8*)(W + (or0 + 16*i + lr)*128 + ks*32 + 8*lg);
  __syncthreads();

  f4 acc[4][4] = {};
  #pragma unroll
  for (int ks = 0; ks < 4; ++ks){
    short8 bfr[4];
    #pragma unroll
    for (int j = 0; j < 4; ++j)
      bfr[j] = *(const short8*)(X + (ks*4 + lg)*1024 + swzc(c0w + 16*j + lr)*8);
    #pragma unroll
    for (int i = 0; i < 4; ++i)
      #pragma unroll
      for (int j = 0; j < 4; ++j)
        acc[i][j] = __builtin_amdgcn_mfma_f32_16x16x32_bf16(af[ks][i], bfr[j], acc[i][j], 0, 0, 0);
  }
  #pragma unroll
  for (int i = 0; i < 4; ++i)
    #pragma unroll
    for (int j = 0; j < 4; ++j){
      int col = c0 + c0w + 16*j + lr;
      *(f4*)(dst + (size_t)col*C_ + or0 + 16*i + 4*lg) = acc[i][j];
    }
}

// ---------------------------------------------------------------------------
// K3_STATS: per-channel sum/sumsq of y0 (NO ybuf store; arithmetic == k3_y0)
// ---------------------------------------------------------------------------
__global__ __launch_bounds__(256) void k3_stats(
    const float* __restrict__ pos1, const float* __restrict__ pos2,
    const float* __restrict__ W0, const int* __restrict__ idx,
    const float* __restrict__ F2t, const float* __restrict__ PREt,
    float* __restrict__ partials)
{
  __shared__ float w0a[384];
  __shared__ float ldsS[256];
  int t = threadIdx.x;
  for (int i = t; i < 384; i += 256) w0a[i] = W0[(i/3)*259 + (i%3)];
  __syncthreads();
  int cloc = t & 15, chg = t >> 4, ch0 = chg*8;
  float wx[8], wy[8], wz[8];
  #pragma unroll
  for (int e = 0; e < 8; ++e){
    wx[e] = w0a[(ch0+e)*3]; wy[e] = w0a[(ch0+e)*3+1]; wz[e] = w0a[(ch0+e)*3+2];
  }
  float s1[8] = {}, s2[8] = {};
  int base = blockIdx.x * 256;
  for (int it = 0; it < 16; ++it){
    int col = base + it*16 + cloc;
    int nabs = col >> 4;
    int b = nabs >> 12, n = nabs & 4095;
    int m = idx[col];
    float dx = pos2[(size_t)(b*3+0)*N_ + m] - pos1[(size_t)(b*3+0)*N_ + n];
    float dy = pos2[(size_t)(b*3+1)*N_ + m] - pos1[(size_t)(b*3+1)*N_ + n];
    float dz = pos2[(size_t)(b*3+2)*N_ + m] - pos1[(size_t)(b*3+2)*N_ + n];
    const float* f2 = F2t  + ((size_t)b*N_ + m)*C_ + ch0;
    const float* pr = PREt + ((size_t)b*N_ + n)*C_ + ch0;
    #pragma unroll
    for (int e = 0; e < 8; ++e){
      float y = f2[e] + pr[e];
      y = fmaf(wx[e], dx, y); y = fmaf(wy[e], dy, y); y = fmaf(wz[e], dz, y);
      s1[e] += y; s2[e] = fmaf(y, y, s2[e]);
    }
  }
  #pragma unroll
  for (int e = 0; e < 8; ++e){
    float a = s1[e], q = s2[e];
    #pragma unroll
    for (int sft = 1; sft < 16; sft <<= 1){ a += __shfl_xor(a, sft); q += __shfl_xor(q, sft); }
    if (cloc == 0){ ldsS[ch0 + e] = a; ldsS[128 + ch0 + e] = q; }
  }
  __syncthreads();
  partials[(size_t)blockIdx.x*256 + t] = ldsS[t];
}

// ---------------------------------------------------------------------------
// Stats reduction + BN coef
// ---------------------------------------------------------------------------
__global__ __launch_bounds__(256) void reduce1(const float* __restrict__ partials,
                                               float* __restrict__ partial2)
{
  int t = threadIdx.x, r0 = blockIdx.x*32;
  float a = 0.f;
  #pragma unroll 4
  for (int i = 0; i < 32; ++i) a += partials[(size_t)(r0+i)*256 + t];
  partial2[(size_t)blockIdx.x*256 + t] = a;
}

__global__ __launch_bounds__(256) void finalize(const float* __restrict__ partial2, int rows,
    const float* __restrict__ g, const float* __restrict__ bb,
    float* __restrict__ cA, float* __restrict__ cB)
{
  __shared__ float sh[256];
  int t = threadIdx.x;
  float a = 0.f;
  for (int i = 0; i < rows; ++i) a += partial2[(size_t)i*256 + t];
  sh[t] = a;
  __syncthreads();
  if (t < 128){
    float mu = sh[t] / CNT_F;
    float var = sh[128 + t] / CNT_F - mu*mu;
    float A = g[t] * rsqrtf(var + EPS_);
    cA[t] = A; cB[t] = bb[t] - mu*A;
  }
}

// ---------------------------------------------------------------------------
// LAYER1 FUSED: recompute y0 (== k3 arithmetic), BN0+relu -> X, MFMA W1,
// stats of y1, transpose, write y1 bf16 to ybuf.
// ---------------------------------------------------------------------------
__global__ __launch_bounds__(256,2) void layer1_fused(
    const float* __restrict__ pos1, const float* __restrict__ pos2,
    const float* __restrict__ W0, const int* __restrict__ idx,
    const float* __restrict__ F2t, const float* __restrict__ PREt,
    unsigned short* __restrict__ ybuf,
    const unsigned short* __restrict__ Wbf,
    const float* __restrict__ cA, const float* __restrict__ cB,
    float* __restrict__ partials)
{
  __shared__ __align__(16) char lds[40960];
  unsigned short* X = (unsigned short*)lds;            // 32KB
  float* ldsA = (float*)(lds + 32768);                 // 128
  float* ldsB = ldsA + 128;                            // 128
  float* w0a  = ldsB + 128;                            // 384
  float* ldsS = w0a + 384;                             // 512
  int t = threadIdx.x;
  int c0 = blockIdx.x * 128;
  if (t < 128){ ldsA[t] = cA[t]; ldsB[t] = cB[t]; }
  for (int i = t; i < 384; i += 256) w0a[i] = W0[(i/3)*259 + (i%3)];
  ldsS[t] = 0.f; ldsS[256 + t] = 0.f;
  __syncthreads();

  int lane = t & 63, w = t >> 6;
  int or0 = (w >> 1)*64, c0w = (w & 1)*64;
  int lr = lane & 15, lg = lane >> 4;

  // phase 1: y0 recompute + BN0 + relu -> X (bf16, swizzled)
  {
    int colL = t >> 1, half = t & 1;
    int col = c0 + colL;
    int nabs = col >> 4;
    int b = nabs >> 12, n = nabs & 4095;
    int m = idx[col];
    float dx = pos2[(size_t)(b*3+0)*N_ + m] - pos1[(size_t)(b*3+0)*N_ + n];
    float dy = pos2[(size_t)(b*3+1)*N_ + m] - pos1[(size_t)(b*3+1)*N_ + n];
    float dz = pos2[(size_t)(b*3+2)*N_ + m] - pos1[(size_t)(b*3+2)*N_ + n];
    const float* f2 = F2t  + ((size_t)b*N_ + m)*C_ + half*64;
    const float* pr = PREt + ((size_t)b*N_ + n)*C_ + half*64;
    int sc = swzc(colL);
    #pragma unroll
    for (int cc = 0; cc < 8; ++cc){
      int ch0 = half*64 + cc*8;
      f4 a0 = *(const f4*)(f2 + cc*8), a1 = *(const f4*)(f2 + cc*8 + 4);
      f4 b0 = *(const f4*)(pr + cc*8), b1 = *(const f4*)(pr + cc*8 + 4);
      short8 xv;
      #pragma unroll
      for (int e = 0; e < 8; ++e){
        int ch = ch0 + e;
        float fv = (e < 4 ? a0[e] : a1[e-4]);
        float pv = (e < 4 ? b0[e] : b1[e-4]);
        float y = fv + pv;
        y = fmaf(w0a[ch*3], dx, y); y = fmaf(w0a[ch*3+1], dy, y); y = fmaf(w0a[ch*3+2], dz, y);
        float v = fmaf(y, ldsA[ch], ldsB[ch]);
        v = v > 0.f ? v : 0.f;
        xv[e] = (short)f2bf(v);
      }
      *(short8*)(X + (ch0 >> 3)*1024 + sc*8) = xv;
    }
  }

  short8 af[4][4];
  #pragma unroll
  for (int ks = 0; ks < 4; ++ks)
    #pragma unroll
    for (int i = 0; i < 4; ++i)
      af[ks][i] = *(const short8*)(Wbf + (or0 + 16*i + lr)*128 + ks*32 + 8*lg);
  __syncthreads();

  // phase 2: MFMA
  f4 acc[4][4] = {};
  #pragma unroll
  for (int ks = 0; ks < 4; ++ks){
    short8 bfr[4];
    #pragma unroll
    for (int j = 0; j < 4; ++j)
      bfr[j] = *(const short8*)(X + (ks*4 + lg)*1024 + swzc(c0w + 16*j + lr)*8);
    #pragma unroll
    for (int i = 0; i < 4; ++i)
      #pragma unroll
      for (int j = 0; j < 4; ++j)
        acc[i][j] = __builtin_amdgcn_mfma_f32_16x16x32_bf16(af[ks][i], bfr[j], acc[i][j], 0, 0, 0);
  }

  // stats of raw y1
  #pragma unroll
  for (int i = 0; i < 4; ++i)
    #pragma unroll
    for (int e = 0; e < 4; ++e){
      float a0 = acc[i][0][e], a1 = acc[i][1][e], a2 = acc[i][2][e], a3 = acc[i][3][e];
      float s1 = (a0 + a1) + (a2 + a3);
      float s2 = (a0*a0 + a1*a1) + (a2*a2 + a3*a3);
      #pragma unroll
      for (int sft = 1; sft < 16; sft <<= 1){ s1 += __shfl_xor(s1, sft); s2 += __shfl_xor(s2, sft); }
      if (lr == 0){
        int o = or0 + 16*i + 4*lg + e;
        ldsS[(w & 1)*256 + o] = s1;
        ldsS[(w & 1)*256 + 128 + o] = s2;
      }
    }

  __syncthreads();                            // all X reads done
  unsigned short* OT = (unsigned short*)lds;  // [128 col][136] bf16
  #pragma unroll
  for (int i = 0; i < 4; ++i)
    #pragma unroll
    for (int j = 0; j < 4; ++j){
      int col = c0w + 16*j + lr;
      int o0 = or0 + 16*i + 4*lg;
      unsigned long long pv =
          (unsigned long long)f2bf(acc[i][j][0])
        | ((unsigned long long)f2bf(acc[i][j][1]) << 16)
        | ((unsigned long long)f2bf(acc[i][j][2]) << 32)
        | ((unsigned long long)f2bf(acc[i][j][3]) << 48);
      *(unsigned long long*)(OT + col*136 + o0) = pv;
    }
  __syncthreads();
  {
    int colL = t >> 1, half = t & 1;
    unsigned short* dst = ybuf + (size_t)(c0 + colL)*128 + half*64;
    #pragma unroll
    for (int cc = 0; cc < 8; ++cc){
      short8 v = *(const short8*)(OT + colL*136 + half*64 + cc*8);
      *(short8*)(dst + cc*8) = v;
    }
  }
  __syncthreads();
  partials[(size_t)blockIdx.x*256 + t] = ldsS[t] + ldsS[256 + t];
}

// ---------------------------------------------------------------------------
// Layer GEMM (LAST layer): x = relu(A*y1+B), y2 = W2 @ x, in-reg K-max.
// ---------------------------------------------------------------------------
__global__ __launch_bounds__(256,2) void layer_gemm_last(
    unsigned short* ybuf,
    const unsigned short* __restrict__ Wbf,
    const float* __restrict__ cA, const float* __restrict__ cB,
    float* __restrict__ y2max,
    float* __restrict__ partials)
{
  __shared__ __align__(16) char lds[38912];
  unsigned short* X = (unsigned short*)lds;      // 32KB
  float* ldsA = (float*)(lds + 34816);
  float* ldsB = ldsA + 128;
  float* ldsS = ldsB + 128;                      // [2][256]
  int t = threadIdx.x;
  int c0 = blockIdx.x * 128;
  if (t < 128){ ldsA[t] = cA[t]; ldsB[t] = cB[t]; }
  ldsS[t] = 0.f; ldsS[256 + t] = 0.f;

  int lane = t & 63, w = t >> 6;
  int or0 = (w >> 1)*64, c0w = (w & 1)*64;
  int lr = lane & 15, lg = lane >> 4;
  short8 af[4][4];
  #pragma unroll
  for (int ks = 0; ks < 4; ++ks)
    #pragma unroll
    for (int i = 0; i < 4; ++i)
      af[ks][i] = *(const short8*)(Wbf + (or0 + 16*i + lr)*128 + ks*32 + 8*lg);
  __syncthreads();

  {
    int colL = t >> 1, half = t & 1;
    const unsigned short* src = ybuf + (size_t)(c0 + colL)*128 + half*64;
    int sc = swzc(colL);
    #pragma unroll
    for (int cc = 0; cc < 8; ++cc){
      int ch0 = half*64 + cc*8;
      short8 yv = *(const short8*)(src + cc*8);
      short8 xv;
      #pragma unroll
      for (int e = 0; e < 8; ++e){
        float f = bf2f((unsigned short)yv[e]);
        float v = fmaf(f, ldsA[ch0 + e], ldsB[ch0 + e]);
        v = v > 0.f ? v : 0.f;
        xv[e] = (short)f2bf(v);
      }
      *(short8*)(X + (ch0 >> 3)*1024 + sc*8) = xv;
    }
  }
  __syncthreads();

  f4 acc[4][4] = {};
  #pragma unroll
  for (int ks = 0; ks < 4; ++ks){
    short8 bfr[4];
    #pragma unroll
    for (int j = 0; j < 4; ++j)
      bfr[j] = *(const short8*)(X + (ks*4 + lg)*1024 + swzc(c0w + 16*j + lr)*8);
    #pragma unroll
    for (int i = 0; i < 4; ++i)
      #pragma unroll
      for (int j = 0; j < 4; ++j)
        acc[i][j] = __builtin_amdgcn_mfma_f32_16x16x32_bf16(af[ks][i], bfr[j], acc[i][j], 0, 0, 0);
  }

  #pragma unroll
  for (int i = 0; i < 4; ++i)
    #pragma unroll
    for (int e = 0; e < 4; ++e){
      float a0 = acc[i][0][e], a1 = acc[i][1][e], a2 = acc[i][2][e], a3 = acc[i][3][e];
      float s1 = (a0 + a1) + (a2 + a3);
      float s2 = (a0*a0 + a1*a1) + (a2*a2 + a3*a3);
      #pragma unroll
      for (int sft = 1; sft < 16; sft <<= 1){ s1 += __shfl_xor(s1, sft); s2 += __shfl_xor(s2, sft); }
      if (lr == 0){
        int o = or0 + 16*i + 4*lg + e;
        ldsS[(w & 1)*256 + o] = s1;
        ldsS[(w & 1)*256 + 128 + o] = s2;
      }
    }

  float keep[4][4] = {};
  #pragma unroll
  for (int j = 0; j < 4; ++j)
    #pragma unroll
    for (int i = 0; i < 4; ++i)
      #pragma unroll
      for (int e = 0; e < 4; ++e){
        float v = acc[i][j][e];
        #pragma unroll
        for (int sft = 1; sft < 16; sft <<= 1) v = fmaxf(v, __shfl_xor(v, sft));
        if (lr == j) keep[i][e] = v;
      }
  if (lr < 4){
    int colg = c0 + c0w + 16*lr;
    int nabs = colg >> 4;
    float* dst = y2max + (size_t)nabs*C_;
    #pragma unroll
    for (int i = 0; i < 4; ++i){
      f4 v; v.x = keep[i][0]; v.y = keep[i][1]; v.z = keep[i][2]; v.w = keep[i][3];
      *(f4*)(dst + or0 + 16*i + 4*lg) = v;
    }
  }
  __syncthreads();
  partials[(size_t)blockIdx.x*256 + t] = ldsS[t] + ldsS[256 + t];
}

// ---------------------------------------------------------------------------
// K7: out[b][o][n] = relu(A2*y2max[b][n][o] + B2)   (LDS transpose)
// ---------------------------------------------------------------------------
__global__ __launch_bounds__(256) void k7_out(
    const float* __restrict__ y2max, const float* __restrict__ cA,
    const float* __restrict__ cB, float* __restrict__ outF)
{
  __shared__ __align__(16) float T[128*65];
  int t = threadIdx.x, bid = blockIdx.x;
  int b = bid >> 6, n0 = (bid & 63)*64;
  {
    int nl = t >> 2, o0 = (t & 3)*32;
    const float* src = y2max + ((size_t)b*N_ + n0 + nl)*C_ + o0;
    #pragma unroll
    for (int jj = 0; jj < 8; ++jj){
      f4 v = *(const f4*)(src + jj*4);
      T[(o0 + jj*4 + 0)*65 + nl] = v.x;
      T[(o0 + jj*4 + 1)*65 + nl] = v.y;
      T[(o0 + jj*4 + 2)*65 + nl] = v.z;
      T[(o0 + jj*4 + 3)*65 + nl] = v.w;
    }
  }
  __syncthreads();
  {
    int o = t >> 1, half = t & 1;
    float A = cA[o], Bb = cB[o];
    float* dst = outF + ((size_t)b*C_ + o)*N_ + n0 + half*32;
    #pragma unroll
    for (int jj = 0; jj < 8; ++jj){
      f4 v;
      float x0 = fmaf(T[o*65 + half*32 + jj*4+0], A, Bb);
      float x1 = fmaf(T[o*65 + half*32 + jj*4+1], A, Bb);
      float x2 = fmaf(T[o*65 + half*32 + jj*4+2], A, Bb);
      float x3 = fmaf(T[o*65 + half*32 + jj*4+3], A, Bb);
      v.x = x0 > 0.f ? x0 : 0.f; v.y = x1 > 0.f ? x1 : 0.f;
      v.z = x2 > 0.f ? x2 : 0.f; v.w = x3 > 0.f ? x3 : 0.f;
      *(f4*)(dst + jj*4) = v;
    }
  }
}

// ---------------------------------------------------------------------------
extern "C" void kernel_launch(void* const* d_in, const int* in_sizes, int n_in,
                              void* d_out, int out_size, void* d_ws, size_t ws_size,
                              hipStream_t stream)
{
  (void)in_sizes; (void)n_in; (void)out_size; (void)ws_size;
  const float* pos1  = (const float*)d_in[0];
  const float* pos2  = (const float*)d_in[1];
  const float* feat1 = (const float*)d_in[2];
  const float* feat2 = (const float*)d_in[3];
  const float* W0 = (const float*)d_in[4];
  const float* W1 = (const float*)d_in[5];
  const float* W2 = (const float*)d_in[6];
  const float* g0 = (const float*)d_in[7];
  const float* g1 = (const float*)d_in[8];
  const float* g2 = (const float*)d_in[9];
  const float* b0 = (const float*)d_in[10];
  const float* b1 = (const float*)d_in[11];
  const float* b2 = (const float*)d_in[12];

  char* ws = (char*)d_ws;
  size_t off = 0;
  auto alloc = [&](size_t bytes){ size_t r = off; off += (bytes + 255) & ~(size_t)255; return r; };
  int*   idx     = (int*)  (ws + alloc((size_t)COLS_TOT*4));       // 1 MB
  float* F2t     = (float*)(ws + alloc((size_t)NQ*C_*4));          // 8 MB
  float* PREt    = (float*)(ws + alloc((size_t)NQ*C_*4));          // 8 MB
  unsigned short* ybuf = (unsigned short*)(ws + alloc((size_t)COLS_TOT*C_*2)); // 64 MiB
  float* y2max   = (float*)(ws + alloc((size_t)NQ*C_*4));          // 8 MB
  float* partials= (float*)(ws + alloc((size_t)2048*256*4));       // 2 MB
  float* partial2= (float*)(ws + alloc((size_t)64*256*4));
  float* coef    = (float*)(ws + alloc((size_t)6*128*4));
  unsigned short* W0bb = (unsigned short*)(ws + alloc(16384*2));
  unsigned short* W0cb = (unsigned short*)(ws + alloc(16384*2));
  unsigned short* W1b  = (unsigned short*)(ws + alloc(16384*2));
  unsigned short* W2b  = (unsigned short*)(ws + alloc(16384*2));

  // KNN scratch ALIASES ybuf (ybuf first written by layer1_fused, after merge)
  float* knn_d = (float*)ybuf;                                 // 16.8 MB
  int*   knn_i = (int*)((char*)ybuf + (size_t)NQ*256*4);       // 16.8 MB

  float* cA0 = coef,       *cB0 = coef + 128;
  float* cA1 = coef + 256, *cB1 = coef + 384;
  float* cA2 = coef + 512, *cB2 = coef + 640;

  wconv<<<256, 256, 0, stream>>>(W0, W1, W2, W0bb, W0cb, W1b, W2b);
  knn_chunk<<<1024, 256, 0, stream>>>(pos1, pos2, knn_d, knn_i);
  knn_merge<<<64, 256, 0, stream>>>(knn_d, knn_i, idx);
  p1_gemm<<<256, 256, 0, stream>>>(feat2, feat1, W0bb, W0cb, F2t, PREt);
  k3_stats<<<1024, 256, 0, stream>>>(pos1, pos2, W0, idx, F2t, PREt, partials);
  reduce1<<<32, 256, 0, stream>>>(partials, partial2);
  finalize<<<1, 256, 0, stream>>>(partial2, 32, g0, b0, cA0, cB0);
  layer1_fused<<<2048, 256, 0, stream>>>(pos1, pos2, W0, idx, F2t, PREt,
                                          ybuf, W1b, cA0, cB0, partials);
  reduce1<<<64, 256, 0, stream>>>(partials, partial2);
  finalize<<<1, 256, 0, stream>>>(partial2, 64, g1, b1, cA1, cB1);
  layer_gemm_last<<<2048, 256, 0, stream>>>(ybuf, W2b, cA1, cB1, y2max, partials);
  reduce1<<<64, 256, 0, stream>>>(partials, partial2);
  finalize<<<1, 256, 0, stream>>>(partial2, 64, g2, b2, cA2, cB2);
  k7_out<<<256, 256, 0, stream>>>(y2max, cA2, cB2, (float*)d_out + (size_t)B_*3*N_);
  hipMemcpyAsync(d_out, d_in[0], (size_t)B_*3*N_*4, hipMemcpyDeviceToDevice, stream);
}

// Round 16
// 365.241 us; speedup vs baseline: 1.1618x; 1.1618x over previous
//
#include <hip/hip_runtime.h>

#define B_ 4
#define N_ 4096
#define K_ 16
#define C_ 128
#define NQ (B_*N_)            // 16384 query points
#define COLS_TOT (NQ*K_)      // 262144 (b,n,k) columns
#define CNT_F 262144.0f
#define EPS_ 1e-5f

typedef __attribute__((ext_vector_type(8))) short short8;
typedef __attribute__((ext_vector_type(4))) float f4;
typedef __attribute__((ext_vector_type(4))) int i4;
typedef unsigned long long u64;

__device__ __forceinline__ unsigned short f2bf(float f){
  unsigned u = __builtin_bit_cast(unsigned, f);
  u = u + 0x7fffu + ((u >> 16) & 1u);     // RNE
  return (unsigned short)(u >> 16);
}
__device__ __forceinline__ float bf2f(unsigned short h){
  return __builtin_bit_cast(float, ((unsigned)h) << 16);
}
__device__ __forceinline__ int swzc(int c){ return c ^ ((c >> 3) & 7); }

// ---------------------------------------------------------------------------
// Weight conversion: W0b=W0[:,3:131], W0c=W0[:,131:259], W1, W2 -> bf16
// ---------------------------------------------------------------------------
__global__ __launch_bounds__(256) void wconv(
    const float* __restrict__ W0, const float* __restrict__ W1, const float* __restrict__ W2,
    unsigned short* __restrict__ W0b, unsigned short* __restrict__ W0c,
    unsigned short* __restrict__ W1b, unsigned short* __restrict__ W2b)
{
  int i = blockIdx.x * 256 + threadIdx.x;
  int sel = i >> 14, r = i & 16383;
  int o = r >> 7, c = r & 127;
  float v; unsigned short* dst;
  if (sel == 0)      { v = W0[o*259 + 3   + c]; dst = W0b; }
  else if (sel == 1) { v = W0[o*259 + 131 + c]; dst = W0c; }
  else if (sel == 2) { v = W1[o*128 + c];       dst = W1b; }
  else               { v = W2[o*128 + c];       dst = W2b; }
  dst[r] = f2bf(v);
}

// ---------------------------------------------------------------------------
// KNN stage 1 — BITONIC top-16 on packed u64 keys (branch-free, uniform cost).
// key = (ordbits(d) << 12) | m : total order == (d asc, m asc) == verified
// selection order. Distance = sgemm-mirror fp32 (VERIFIED r10):
//   sq  = rn(rn(rn(x*x)+rn(y*y))+rn(z*z))
//   dot = fma(z1,z2, fma(y1,y2, rn(x1*x2)))
//   d   = rn(rn(qs+sq) - 2*dot)
// 16 chunks x 256 candidates; grid 1024. Output: u64 key lists, [entry][q].
// ---------------------------------------------------------------------------
__global__ __launch_bounds__(256) void knn_chunk(
    const float* __restrict__ pos1, const float* __restrict__ pos2,
    u64* __restrict__ kout)
{
  __shared__ __align__(16) float pts[256*4];    // 4 KB
  int bx = blockIdx.x;
  int b = bx >> 8, rest = bx & 255, ngrp = rest >> 4, chunk = rest & 15;
  int t = threadIdx.x;
  int m0 = chunk * 256;
  const float* p2 = pos2 + (size_t)b*3*N_;
  {
    int m = m0 + t;
    float x = p2[m], y = p2[N_ + m], z = p2[2*N_ + m];
    float sq = __fadd_rn(__fadd_rn(__fmul_rn(x,x), __fmul_rn(y,y)), __fmul_rn(z,z));
    f4 v; v.x = x; v.y = y; v.z = z; v.w = sq;
    *(f4*)(pts + t*4) = v;
  }
  __syncthreads();

  int n = ngrp*256 + t;
  const float* p1 = pos1 + (size_t)b*3*N_;
  float qx = p1[n], qy = p1[N_ + n], qz = p1[2*N_ + n];
  float qs = __fadd_rn(__fadd_rn(__fmul_rn(qx,qx), __fmul_rn(qy,qy)), __fmul_rn(qz,qz));

  u64 list[16];
  #pragma unroll
  for (int j = 0; j < 16; ++j) list[j] = ~0ull;

  #pragma unroll 1
  for (int tile = 0; tile < 16; ++tile){
    u64 tk[16];
    // distances + pack
    #pragma unroll
    for (int e = 0; e < 16; ++e){
      int it = tile*16 + e;
      f4 c = *(const f4*)(pts + it*4);
      float dot = __builtin_fmaf(qz, c.z,
                    __builtin_fmaf(qy, c.y, __fmul_rn(qx, c.x)));
      float d = __fsub_rn(__fadd_rn(qs, c.w), __fmul_rn(2.0f, dot));
      d = __fadd_rn(d, 0.0f);                       // canonicalize -0 -> +0
      unsigned u = __builtin_bit_cast(unsigned, d);
      u ^= (unsigned)((int)u >> 31) | 0x80000000u;  // order-preserving map
      tk[e] = ((u64)u << 12) | (unsigned)(m0 + it);
    }
    // bitonic sort ascending (textbook network, n=16)
    #pragma unroll
    for (int k = 2; k <= 16; k <<= 1)
      #pragma unroll
      for (int j2 = k >> 1; j2 > 0; j2 >>= 1)
        #pragma unroll
        for (int i = 0; i < 16; ++i){
          int l = i ^ j2;
          if (l > i){
            bool up = ((i & k) == 0);
            u64 a = tk[i], bb = tk[l];
            bool sw = up ? (a > bb) : (a < bb);
            u64 lo = sw ? bb : a, hi = sw ? a : bb;
            tk[i] = lo; tk[l] = hi;
          }
        }
    // lower-half of union (both ascending): min(list[i], tk[15-i]) is bitonic
    u64 m16[16];
    #pragma unroll
    for (int i = 0; i < 16; ++i){
      u64 a = list[i], bb = tk[15 - i];
      m16[i] = a < bb ? a : bb;
    }
    // bitonic clean -> ascending
    #pragma unroll
    for (int j2 = 8; j2 > 0; j2 >>= 1)
      #pragma unroll
      for (int i = 0; i < 16; ++i){
        int l = i ^ j2;
        if (l > i){
          u64 a = m16[i], bb = m16[l];
          bool sw = a > bb;
          m16[i] = sw ? bb : a; m16[l] = sw ? a : bb;
        }
      }
    #pragma unroll
    for (int i = 0; i < 16; ++i) list[i] = m16[i];
  }

  int q = b*N_ + n;                       // consecutive per lane -> coalesced
  #pragma unroll
  for (int j = 0; j < 16; ++j)
    kout[(size_t)(chunk*16 + j)*NQ + q] = list[j];
}

// KNN stage 2: merge 16 sorted 16-lists of u64 keys (coalesced [entry][q]).
// Chain insert, ascending-list early-exit. Extract m = key & 0xFFF.
__global__ __launch_bounds__(256) void knn_merge(
    const u64* __restrict__ kin, int* __restrict__ idxout)
{
  int q = blockIdx.x*256 + threadIdx.x;
  u64 list[16];
  #pragma unroll
  for (int j = 0; j < 16; ++j) list[j] = ~0ull;
  #pragma unroll 1
  for (int l = 0; l < 16; ++l){
    u64 lv[16];
    #pragma unroll
    for (int j = 0; j < 16; ++j)
      lv[j] = kin[(size_t)(l*16 + j)*NQ + q];
    bool dead = false;
    #pragma unroll
    for (int j = 0; j < 16; ++j){
      bool ins = !dead && (list[15] > lv[j]);
      dead = !ins;                       // ascending list: first fail kills rest
      if (__any(ins)){
        if (ins){
          u64 key = lv[j];
          bool cm = list[14] > key;
          list[15] = cm ? list[14] : key;
          #pragma unroll
          for (int jj = 14; jj >= 1; --jj){
            bool cj = cm;
            cm = list[jj-1] > key;
            list[jj] = cj ? (cm ? list[jj-1] : key) : list[jj];
          }
          list[0] = cm ? key : list[0];
        }
      }
    }
  }
  #pragma unroll
  for (int j = 0; j < 4; ++j){
    i4 v;
    v.x = (int)(list[j*4]   & 0xFFF); v.y = (int)(list[j*4+1] & 0xFFF);
    v.z = (int)(list[j*4+2] & 0xFFF); v.w = (int)(list[j*4+3] & 0xFFF);
    *(i4*)(idxout + (size_t)q*16 + j*4) = v;
  }
}

// ---------------------------------------------------------------------------
// P1: F2t[b][m][o] = (W0b @ feature2), PREt[b][n][o] = (W0c @ feature1)
// ---------------------------------------------------------------------------
__global__ __launch_bounds__(256) void p1_gemm(
    const float* __restrict__ feat2, const float* __restrict__ feat1,
    const unsigned short* __restrict__ W0b, const unsigned short* __restrict__ W0c,
    float* __restrict__ F2t, float* __restrict__ PREt)
{
  __shared__ __align__(16) unsigned short X[16*128*8];  // 32KB
  int bid = blockIdx.x;
  int sel = bid >> 7;
  const float* src = sel ? feat1 : feat2;
  const unsigned short* W = sel ? W0c : W0b;
  float* dst = sel ? PREt : F2t;
  int c0 = (bid & 127) * 128;
  int b = c0 >> 12, mm0 = c0 & 4095;
  int t = threadIdx.x;
  {
    int colt = t & 127, chh = t >> 7;      // 2 channels per iteration
    #pragma unroll 4
    for (int it = 0; it < 64; ++it){
      int ch = it*2 + chh;
      float v = src[((size_t)b*C_ + ch)*N_ + mm0 + colt];
      X[(ch >> 3)*1024 + swzc(colt)*8 + (ch & 7)] = f2bf(v);
    }
  }
  int lane = t & 63, w = t >> 6;
  int or0 = (w >> 1)*64, c0w = (w & 1)*64;
  int lr = lane & 15, lg = lane >> 4;
  short8 af[4][4];
  #pragma unroll
  for (int ks = 0; ks < 4; ++ks)
    #pragma unroll
    for (int i = 0; i < 4; ++i)
      af[ks][i] = *(const short8*)(W + (or0 + 16*i + lr)*128 + ks*32 + 8*lg);
  __syncthreads();

  f4 acc[4][4] = {};
  #pragma unroll
  for (int ks = 0; ks < 4; ++ks){
    short8 bfr[4];
    #pragma unroll
    for (int j = 0; j < 4; ++j)
      bfr[j] = *(const short8*)(X + (ks*4 + lg)*1024 + swzc(c0w + 16*j + lr)*8);
    #pragma unroll
    for (int i = 0; i < 4; ++i)
      #pragma unroll
      for (int j = 0; j < 4; ++j)
        acc[i][j] = __builtin_amdgcn_mfma_f32_16x16x32_bf16(af[ks][i], bfr[j], acc[i][j], 0, 0, 0);
  }
  #pragma unroll
  for (int i = 0; i < 4; ++i)
    #pragma unroll
    for (int j = 0; j < 4; ++j){
      int col = c0 + c0w + 16*j + lr;
      *(f4*)(dst + (size_t)col*C_ + or0 + 16*i + 4*lg) = acc[i][j];
    }
}

// ---------------------------------------------------------------------------
// K3_STATS: per-channel sum/sumsq of y0 (NO ybuf store; arithmetic == k3_y0)
// ---------------------------------------------------------------------------
__global__ __launch_bounds__(256) void k3_stats(
    const float* __restrict__ pos1, const float* __restrict__ pos2,
    const float* __restrict__ W0, const int* __restrict__ idx,
    const float* __restrict__ F2t, const float* __restrict__ PREt,
    float* __restrict__ partials)
{
  __shared__ float w0a[384];
  __shared__ float ldsS[256];
  int t = threadIdx.x;
  for (int i = t; i < 384; i += 256) w0a[i] = W0[(i/3)*259 + (i%3)];
  __syncthreads();
  int cloc = t & 15, chg = t >> 4, ch0 = chg*8;
  float wx[8], wy[8], wz[8];
  #pragma unroll
  for (int e = 0; e < 8; ++e){
    wx[e] = w0a[(ch0+e)*3]; wy[e] = w0a[(ch0+e)*3+1]; wz[e] = w0a[(ch0+e)*3+2];
  }
  float s1[8] = {}, s2[8] = {};
  int base = blockIdx.x * 256;
  for (int it = 0; it < 16; ++it){
    int col = base + it*16 + cloc;
    int nabs = col >> 4;
    int b = nabs >> 12, n = nabs & 4095;
    int m = idx[col];
    float dx = pos2[(size_t)(b*3+0)*N_ + m] - pos1[(size_t)(b*3+0)*N_ + n];
    float dy = pos2[(size_t)(b*3+1)*N_ + m] - pos1[(size_t)(b*3+1)*N_ + n];
    float dz = pos2[(size_t)(b*3+2)*N_ + m] - pos1[(size_t)(b*3+2)*N_ + n];
    const float* f2 = F2t  + ((size_t)b*N_ + m)*C_ + ch0;
    const float* pr = PREt + ((size_t)b*N_ + n)*C_ + ch0;
    #pragma unroll
    for (int e = 0; e < 8; ++e){
      float y = f2[e] + pr[e];
      y = fmaf(wx[e], dx, y); y = fmaf(wy[e], dy, y); y = fmaf(wz[e], dz, y);
      s1[e] += y; s2[e] = fmaf(y, y, s2[e]);
    }
  }
  #pragma unroll
  for (int e = 0; e < 8; ++e){
    float a = s1[e], q = s2[e];
    #pragma unroll
    for (int sft = 1; sft < 16; sft <<= 1){ a += __shfl_xor(a, sft); q += __shfl_xor(q, sft); }
    if (cloc == 0){ ldsS[ch0 + e] = a; ldsS[128 + ch0 + e] = q; }
  }
  __syncthreads();
  partials[(size_t)blockIdx.x*256 + t] = ldsS[t];
}

// ---------------------------------------------------------------------------
// Stats reduction + BN coef
// ---------------------------------------------------------------------------
__global__ __launch_bounds__(256) void reduce1(const float* __restrict__ partials,
                                               float* __restrict__ partial2)
{
  int t = threadIdx.x, r0 = blockIdx.x*32;
  float a = 0.f;
  #pragma unroll 4
  for (int i = 0; i < 32; ++i) a += partials[(size_t)(r0+i)*256 + t];
  partial2[(size_t)blockIdx.x*256 + t] = a;
}

__global__ __launch_bounds__(256) void finalize(const float* __restrict__ partial2, int rows,
    const float* __restrict__ g, const float* __restrict__ bb,
    float* __restrict__ cA, float* __restrict__ cB)
{
  __shared__ float sh[256];
  int t = threadIdx.x;
  float a = 0.f;
  for (int i = 0; i < rows; ++i) a += partial2[(size_t)i*256 + t];
  sh[t] = a;
  __syncthreads();
  if (t < 128){
    float mu = sh[t] / CNT_F;
    float var = sh[128 + t] / CNT_F - mu*mu;
    float A = g[t] * rsqrtf(var + EPS_);
    cA[t] = A; cB[t] = bb[t] - mu*A;
  }
}

// ---------------------------------------------------------------------------
// LAYER1 FUSED: recompute y0 (== k3 arithmetic), BN0+relu -> X, MFMA W1,
// stats of y1, transpose, write y1 bf16 to ybuf.
// ---------------------------------------------------------------------------
__global__ __launch_bounds__(256,2) void layer1_fused(
    const float* __restrict__ pos1, const float* __restrict__ pos2,
    const float* __restrict__ W0, const int* __restrict__ idx,
    const float* __restrict__ F2t, const float* __restrict__ PREt,
    unsigned short* __restrict__ ybuf,
    const unsigned short* __restrict__ Wbf,
    const float* __restrict__ cA, const float* __restrict__ cB,
    float* __restrict__ partials)
{
  __shared__ __align__(16) char lds[40960];
  unsigned short* X = (unsigned short*)lds;            // 32KB
  float* ldsA = (float*)(lds + 32768);                 // 128
  float* ldsB = ldsA + 128;                            // 128
  float* w0a  = ldsB + 128;                            // 384
  float* ldsS = w0a + 384;                             // 512
  int t = threadIdx.x;
  int c0 = blockIdx.x * 128;
  if (t < 128){ ldsA[t] = cA[t]; ldsB[t] = cB[t]; }
  for (int i = t; i < 384; i += 256) w0a[i] = W0[(i/3)*259 + (i%3)];
  ldsS[t] = 0.f; ldsS[256 + t] = 0.f;
  __syncthreads();

  int lane = t & 63, w = t >> 6;
  int or0 = (w >> 1)*64, c0w = (w & 1)*64;
  int lr = lane & 15, lg = lane >> 4;

  // phase 1: y0 recompute + BN0 + relu -> X (bf16, swizzled)
  {
    int colL = t >> 1, half = t & 1;
    int col = c0 + colL;
    int nabs = col >> 4;
    int b = nabs >> 12, n = nabs & 4095;
    int m = idx[col];
    float dx = pos2[(size_t)(b*3+0)*N_ + m] - pos1[(size_t)(b*3+0)*N_ + n];
    float dy = pos2[(size_t)(b*3+1)*N_ + m] - pos1[(size_t)(b*3+1)*N_ + n];
    float dz = pos2[(size_t)(b*3+2)*N_ + m] - pos1[(size_t)(b*3+2)*N_ + n];
    const float* f2 = F2t  + ((size_t)b*N_ + m)*C_ + half*64;
    const float* pr = PREt + ((size_t)b*N_ + n)*C_ + half*64;
    int sc = swzc(colL);
    #pragma unroll
    for (int cc = 0; cc < 8; ++cc){
      int ch0 = half*64 + cc*8;
      f4 a0 = *(const f4*)(f2 + cc*8), a1 = *(const f4*)(f2 + cc*8 + 4);
      f4 b0 = *(const f4*)(pr + cc*8), b1 = *(const f4*)(pr + cc*8 + 4);
      short8 xv;
      #pragma unroll
      for (int e = 0; e < 8; ++e){
        int ch = ch0 + e;
        float fv = (e < 4 ? a0[e] : a1[e-4]);
        float pv = (e < 4 ? b0[e] : b1[e-4]);
        float y = fv + pv;
        y = fmaf(w0a[ch*3], dx, y); y = fmaf(w0a[ch*3+1], dy, y); y = fmaf(w0a[ch*3+2], dz, y);
        float v = fmaf(y, ldsA[ch], ldsB[ch]);
        v = v > 0.f ? v : 0.f;
        xv[e] = (short)f2bf(v);
      }
      *(short8*)(X + (ch0 >> 3)*1024 + sc*8) = xv;
    }
  }

  short8 af[4][4];
  #pragma unroll
  for (int ks = 0; ks < 4; ++ks)
    #pragma unroll
    for (int i = 0; i < 4; ++i)
      af[ks][i] = *(const short8*)(Wbf + (or0 + 16*i + lr)*128 + ks*32 + 8*lg);
  __syncthreads();

  // phase 2: MFMA
  f4 acc[4][4] = {};
  #pragma unroll
  for (int ks = 0; ks < 4; ++ks){
    short8 bfr[4];
    #pragma unroll
    for (int j = 0; j < 4; ++j)
      bfr[j] = *(const short8*)(X + (ks*4 + lg)*1024 + swzc(c0w + 16*j + lr)*8);
    #pragma unroll
    for (int i = 0; i < 4; ++i)
      #pragma unroll
      for (int j = 0; j < 4; ++j)
        acc[i][j] = __builtin_amdgcn_mfma_f32_16x16x32_bf16(af[ks][i], bfr[j], acc[i][j], 0, 0, 0);
  }

  // stats of raw y1
  #pragma unroll
  for (int i = 0; i < 4; ++i)
    #pragma unroll
    for (int e = 0; e < 4; ++e){
      float a0 = acc[i][0][e], a1 = acc[i][1][e], a2 = acc[i][2][e], a3 = acc[i][3][e];
      float s1 = (a0 + a1) + (a2 + a3);
      float s2 = (a0*a0 + a1*a1) + (a2*a2 + a3*a3);
      #pragma unroll
      for (int sft = 1; sft < 16; sft <<= 1){ s1 += __shfl_xor(s1, sft); s2 += __shfl_xor(s2, sft); }
      if (lr == 0){
        int o = or0 + 16*i + 4*lg + e;
        ldsS[(w & 1)*256 + o] = s1;
        ldsS[(w & 1)*256 + 128 + o] = s2;
      }
    }

  __syncthreads();                            // all X reads done
  unsigned short* OT = (unsigned short*)lds;  // [128 col][136] bf16
  #pragma unroll
  for (int i = 0; i < 4; ++i)
    #pragma unroll
    for (int j = 0; j < 4; ++j){
      int col = c0w + 16*j + lr;
      int o0 = or0 + 16*i + 4*lg;
      unsigned long long pv =
          (unsigned long long)f2bf(acc[i][j][0])
        | ((unsigned long long)f2bf(acc[i][j][1]) << 16)
        | ((unsigned long long)f2bf(acc[i][j][2]) << 32)
        | ((unsigned long long)f2bf(acc[i][j][3]) << 48);
      *(unsigned long long*)(OT + col*136 + o0) = pv;
    }
  __syncthreads();
  {
    int colL = t >> 1, half = t & 1;
    unsigned short* dst = ybuf + (size_t)(c0 + colL)*128 + half*64;
    #pragma unroll
    for (int cc = 0; cc < 8; ++cc){
      short8 v = *(const short8*)(OT + colL*136 + half*64 + cc*8);
      *(short8*)(dst + cc*8) = v;
    }
  }
  __syncthreads();
  partials[(size_t)blockIdx.x*256 + t] = ldsS[t] + ldsS[256 + t];
}

// ---------------------------------------------------------------------------
// Layer GEMM (LAST layer): x = relu(A*y1+B), y2 = W2 @ x, in-reg K-max.
// ---------------------------------------------------------------------------
__global__ __launch_bounds__(256,2) void layer_gemm_last(
    unsigned short* ybuf,
    const unsigned short* __restrict__ Wbf,
    const float* __restrict__ cA, const float* __restrict__ cB,
    float* __restrict__ y2max,
    float* __restrict__ partials)
{
  __shared__ __align__(16) char lds[38912];
  unsigned short* X = (unsigned short*)lds;      // 32KB
  float* ldsA = (float*)(lds + 34816);
  float* ldsB = ldsA + 128;
  float* ldsS = ldsB + 128;                      // [2][256]
  int t = threadIdx.x;
  int c0 = blockIdx.x * 128;
  if (t < 128){ ldsA[t] = cA[t]; ldsB[t] = cB[t]; }
  ldsS[t] = 0.f; ldsS[256 + t] = 0.f;

  int lane = t & 63, w = t >> 6;
  int or0 = (w >> 1)*64, c0w = (w & 1)*64;
  int lr = lane & 15, lg = lane >> 4;
  short8 af[4][4];
  #pragma unroll
  for (int ks = 0; ks < 4; ++ks)
    #pragma unroll
    for (int i = 0; i < 4; ++i)
      af[ks][i] = *(const short8*)(Wbf + (or0 + 16*i + lr)*128 + ks*32 + 8*lg);
  __syncthreads();

  {
    int colL = t >> 1, half = t & 1;
    const unsigned short* src = ybuf + (size_t)(c0 + colL)*128 + half*64;
    int sc = swzc(colL);
    #pragma unroll
    for (int cc = 0; cc < 8; ++cc){
      int ch0 = half*64 + cc*8;
      short8 yv = *(const short8*)(src + cc*8);
      short8 xv;
      #pragma unroll
      for (int e = 0; e < 8; ++e){
        float f = bf2f((unsigned short)yv[e]);
        float v = fmaf(f, ldsA[ch0 + e], ldsB[ch0 + e]);
        v = v > 0.f ? v : 0.f;
        xv[e] = (short)f2bf(v);
      }
      *(short8*)(X + (ch0 >> 3)*1024 + sc*8) = xv;
    }
  }
  __syncthreads();

  f4 acc[4][4] = {};
  #pragma unroll
  for (int ks = 0; ks < 4; ++ks){
    short8 bfr[4];
    #pragma unroll
    for (int j = 0; j < 4; ++j)
      bfr[j] = *(const short8*)(X + (ks*4 + lg)*1024 + swzc(c0w + 16*j + lr)*8);
    #pragma unroll
    for (int i = 0; i < 4; ++i)
      #pragma unroll
      for (int j = 0; j < 4; ++j)
        acc[i][j] = __builtin_amdgcn_mfma_f32_16x16x32_bf16(af[ks][i], bfr[j], acc[i][j], 0, 0, 0);
  }

  #pragma unroll
  for (int i = 0; i < 4; ++i)
    #pragma unroll
    for (int e = 0; e < 4; ++e){
      float a0 = acc[i][0][e], a1 = acc[i][1][e], a2 = acc[i][2][e], a3 = acc[i][3][e];
      float s1 = (a0 + a1) + (a2 + a3);
      float s2 = (a0*a0 + a1*a1) + (a2*a2 + a3*a3);
      #pragma unroll
      for (int sft = 1; sft < 16; sft <<= 1){ s1 += __shfl_xor(s1, sft); s2 += __shfl_xor(s2, sft); }
      if (lr == 0){
        int o = or0 + 16*i + 4*lg + e;
        ldsS[(w & 1)*256 + o] = s1;
        ldsS[(w & 1)*256 + 128 + o] = s2;
      }
    }

  float keep[4][4] = {};
  #pragma unroll
  for (int j = 0; j < 4; ++j)
    #pragma unroll
    for (int i = 0; i < 4; ++i)
      #pragma unroll
      for (int e = 0; e < 4; ++e){
        float v = acc[i][j][e];
        #pragma unroll
        for (int sft = 1; sft < 16; sft <<= 1) v = fmaxf(v, __shfl_xor(v, sft));
        if (lr == j) keep[i][e] = v;
      }
  if (lr < 4){
    int colg = c0 + c0w + 16*lr;
    int nabs = colg >> 4;
    float* dst = y2max + (size_t)nabs*C_;
    #pragma unroll
    for (int i = 0; i < 4; ++i){
      f4 v; v.x = keep[i][0]; v.y = keep[i][1]; v.z = keep[i][2]; v.w = keep[i][3];
      *(f4*)(dst + or0 + 16*i + 4*lg) = v;
    }
  }
  __syncthreads();
  partials[(size_t)blockIdx.x*256 + t] = ldsS[t] + ldsS[256 + t];
}

// ---------------------------------------------------------------------------
// K7: out[b][o][n] = relu(A2*y2max[b][n][o] + B2)   (LDS transpose)
// ---------------------------------------------------------------------------
__global__ __launch_bounds__(256) void k7_out(
    const float* __restrict__ y2max, const float* __restrict__ cA,
    const float* __restrict__ cB, float* __restrict__ outF)
{
  __shared__ __align__(16) float T[128*65];
  int t = threadIdx.x, bid = blockIdx.x;
  int b = bid >> 6, n0 = (bid & 63)*64;
  {
    int nl = t >> 2, o0 = (t & 3)*32;
    const float* src = y2max + ((size_t)b*N_ + n0 + nl)*C_ + o0;
    #pragma unroll
    for (int jj = 0; jj < 8; ++jj){
      f4 v = *(const f4*)(src + jj*4);
      T[(o0 + jj*4 + 0)*65 + nl] = v.x;
      T[(o0 + jj*4 + 1)*65 + nl] = v.y;
      T[(o0 + jj*4 + 2)*65 + nl] = v.z;
      T[(o0 + jj*4 + 3)*65 + nl] = v.w;
    }
  }
  __syncthreads();
  {
    int o = t >> 1, half = t & 1;
    float A = cA[o], Bb = cB[o];
    float* dst = outF + ((size_t)b*C_ + o)*N_ + n0 + half*32;
    #pragma unroll
    for (int jj = 0; jj < 8; ++jj){
      f4 v;
      float x0 = fmaf(T[o*65 + half*32 + jj*4+0], A, Bb);
      float x1 = fmaf(T[o*65 + half*32 + jj*4+1], A, Bb);
      float x2 = fmaf(T[o*65 + half*32 + jj*4+2], A, Bb);
      float x3 = fmaf(T[o*65 + half*32 + jj*4+3], A, Bb);
      v.x = x0 > 0.f ? x0 : 0.f; v.y = x1 > 0.f ? x1 : 0.f;
      v.z = x2 > 0.f ? x2 : 0.f; v.w = x3 > 0.f ? x3 : 0.f;
      *(f4*)(dst + jj*4) = v;
    }
  }
}

// ---------------------------------------------------------------------------
extern "C" void kernel_launch(void* const* d_in, const int* in_sizes, int n_in,
                              void* d_out, int out_size, void* d_ws, size_t ws_size,
                              hipStream_t stream)
{
  (void)in_sizes; (void)n_in; (void)out_size; (void)ws_size;
  const float* pos1  = (const float*)d_in[0];
  const float* pos2  = (const float*)d_in[1];
  const float* feat1 = (const float*)d_in[2];
  const float* feat2 = (const float*)d_in[3];
  const float* W0 = (const float*)d_in[4];
  const float* W1 = (const float*)d_in[5];
  const float* W2 = (const float*)d_in[6];
  const float* g0 = (const float*)d_in[7];
  const float* g1 = (const float*)d_in[8];
  const float* g2 = (const float*)d_in[9];
  const float* b0 = (const float*)d_in[10];
  const float* b1 = (const float*)d_in[11];
  const float* b2 = (const float*)d_in[12];

  char* ws = (char*)d_ws;
  size_t off = 0;
  auto alloc = [&](size_t bytes){ size_t r = off; off += (bytes + 255) & ~(size_t)255; return r; };
  int*   idx     = (int*)  (ws + alloc((size_t)COLS_TOT*4));       // 1 MB
  float* F2t     = (float*)(ws + alloc((size_t)NQ*C_*4));          // 8 MB
  float* PREt    = (float*)(ws + alloc((size_t)NQ*C_*4));          // 8 MB
  unsigned short* ybuf = (unsigned short*)(ws + alloc((size_t)COLS_TOT*C_*2)); // 64 MiB
  float* y2max   = (float*)(ws + alloc((size_t)NQ*C_*4));          // 8 MB
  float* partials= (float*)(ws + alloc((size_t)2048*256*4));       // 2 MB
  float* partial2= (float*)(ws + alloc((size_t)64*256*4));
  float* coef    = (float*)(ws + alloc((size_t)6*128*4));
  unsigned short* W0bb = (unsigned short*)(ws + alloc(16384*2));
  unsigned short* W0cb = (unsigned short*)(ws + alloc(16384*2));
  unsigned short* W1b  = (unsigned short*)(ws + alloc(16384*2));
  unsigned short* W2b  = (unsigned short*)(ws + alloc(16384*2));

  // KNN scratch ALIASES ybuf (33.5 MB < 64 MiB; ybuf first written later)
  u64* knn_k = (u64*)ybuf;

  float* cA0 = coef,       *cB0 = coef + 128;
  float* cA1 = coef + 256, *cB1 = coef + 384;
  float* cA2 = coef + 512, *cB2 = coef + 640;

  wconv<<<256, 256, 0, stream>>>(W0, W1, W2, W0bb, W0cb, W1b, W2b);
  knn_chunk<<<1024, 256, 0, stream>>>(pos1, pos2, knn_k);
  knn_merge<<<64, 256, 0, stream>>>(knn_k, idx);
  p1_gemm<<<256, 256, 0, stream>>>(feat2, feat1, W0bb, W0cb, F2t, PREt);
  k3_stats<<<1024, 256, 0, stream>>>(pos1, pos2, W0, idx, F2t, PREt, partials);
  reduce1<<<32, 256, 0, stream>>>(partials, partial2);
  finalize<<<1, 256, 0, stream>>>(partial2, 32, g0, b0, cA0, cB0);
  layer1_fused<<<2048, 256, 0, stream>>>(pos1, pos2, W0, idx, F2t, PREt,
                                          ybuf, W1b, cA0, cB0, partials);
  reduce1<<<64, 256, 0, stream>>>(partials, partial2);
  finalize<<<1, 256, 0, stream>>>(partial2, 64, g1, b1, cA1, cB1);
  layer_gemm_last<<<2048, 256, 0, stream>>>(ybuf, W2b, cA1, cB1, y2max, partials);
  reduce1<<<64, 256, 0, stream>>>(partials, partial2);
  finalize<<<1, 256, 0, stream>>>(partial2, 64, g2, b2, cA2, cB2);
  k7_out<<<256, 256, 0, stream>>>(y2max, cA2, cB2, (float*)d_out + (size_t)B_*3*N_);
  hipMemcpyAsync(d_out, d_in[0], (size_t)B_*3*N_*4, hipMemcpyDeviceToDevice, stream);
}

// Round 17
// 361.147 us; speedup vs baseline: 1.1750x; 1.0113x over previous
//
#include <hip/hip_runtime.h>

#define B_ 4
#define N_ 4096
#define K_ 16
#define C_ 128
#define NQ (B_*N_)            // 16384 query points
#define COLS_TOT (NQ*K_)      // 262144 (b,n,k) columns
#define CNT_F 262144.0f
#define EPS_ 1e-5f

typedef __attribute__((ext_vector_type(8))) short short8;
typedef __attribute__((ext_vector_type(4))) float f4;
typedef __attribute__((ext_vector_type(4))) int i4;
typedef unsigned long long u64;

__device__ __forceinline__ unsigned short f2bf(float f){
  unsigned u = __builtin_bit_cast(unsigned, f);
  u = u + 0x7fffu + ((u >> 16) & 1u);     // RNE
  return (unsigned short)(u >> 16);
}
__device__ __forceinline__ float bf2f(unsigned short h){
  return __builtin_bit_cast(float, ((unsigned)h) << 16);
}
__device__ __forceinline__ int swzc(int c){ return c ^ ((c >> 3) & 7); }

// ---------------------------------------------------------------------------
// FAT 1: blocks [0,1024) = KNN bitonic top-16 ; blocks [1024,1280) = wconv.
// KNN: key = (ordbits(d) << 32) | m  (order == (d asc, m asc), verified r10/16)
// Distance = sgemm-mirror fp32 (VERIFIED r10).
// ---------------------------------------------------------------------------
__global__ __launch_bounds__(256) void knn_wconv(
    const float* __restrict__ pos1, const float* __restrict__ pos2,
    u64* __restrict__ kout,
    const float* __restrict__ W0, const float* __restrict__ W1,
    const float* __restrict__ W2,
    unsigned short* __restrict__ W0b, unsigned short* __restrict__ W0c,
    unsigned short* __restrict__ W1b, unsigned short* __restrict__ W2b)
{
  if (blockIdx.x >= 1024){
    int i = (blockIdx.x - 1024) * 256 + threadIdx.x;    // 0..65535
    int sel = i >> 14, r = i & 16383;
    int o = r >> 7, c = r & 127;
    float v; unsigned short* dst;
    if (sel == 0)      { v = W0[o*259 + 3   + c]; dst = W0b; }
    else if (sel == 1) { v = W0[o*259 + 131 + c]; dst = W0c; }
    else if (sel == 2) { v = W1[o*128 + c];       dst = W1b; }
    else               { v = W2[o*128 + c];       dst = W2b; }
    dst[r] = f2bf(v);
    return;
  }
  __shared__ __align__(16) float pts[256*4];    // 4 KB
  int bx = blockIdx.x;
  int b = bx >> 8, rest = bx & 255, ngrp = rest >> 4, chunk = rest & 15;
  int t = threadIdx.x;
  int m0 = chunk * 256;
  const float* p2 = pos2 + (size_t)b*3*N_;
  {
    int m = m0 + t;
    float x = p2[m], y = p2[N_ + m], z = p2[2*N_ + m];
    float sq = __fadd_rn(__fadd_rn(__fmul_rn(x,x), __fmul_rn(y,y)), __fmul_rn(z,z));
    f4 v; v.x = x; v.y = y; v.z = z; v.w = sq;
    *(f4*)(pts + t*4) = v;
  }
  __syncthreads();

  int n = ngrp*256 + t;
  const float* p1 = pos1 + (size_t)b*3*N_;
  float qx = p1[n], qy = p1[N_ + n], qz = p1[2*N_ + n];
  float qs = __fadd_rn(__fadd_rn(__fmul_rn(qx,qx), __fmul_rn(qy,qy)), __fmul_rn(qz,qz));

  u64 list[16];
  #pragma unroll
  for (int j = 0; j < 16; ++j) list[j] = ~0ull;

  #pragma unroll 1
  for (int tile = 0; tile < 16; ++tile){
    u64 tk[16];
    #pragma unroll
    for (int e = 0; e < 16; ++e){
      int it = tile*16 + e;
      f4 c = *(const f4*)(pts + it*4);
      float dot = __builtin_fmaf(qz, c.z,
                    __builtin_fmaf(qy, c.y, __fmul_rn(qx, c.x)));
      float d = __fsub_rn(__fadd_rn(qs, c.w), __fmul_rn(2.0f, dot));
      d = __fadd_rn(d, 0.0f);                       // canonicalize -0 -> +0
      unsigned u = __builtin_bit_cast(unsigned, d);
      u ^= (unsigned)((int)u >> 31) | 0x80000000u;  // order-preserving map
      tk[e] = ((u64)u << 32) | (unsigned)(m0 + it); // hi=ord, lo=m (free pack)
    }
    // bitonic sort ascending (n=16)
    #pragma unroll
    for (int k = 2; k <= 16; k <<= 1)
      #pragma unroll
      for (int j2 = k >> 1; j2 > 0; j2 >>= 1)
        #pragma unroll
        for (int i = 0; i < 16; ++i){
          int l = i ^ j2;
          if (l > i){
            bool up = ((i & k) == 0);
            u64 a = tk[i], bb = tk[l];
            bool sw = up ? (a > bb) : (a < bb);
            u64 lo = sw ? bb : a, hi = sw ? a : bb;
            tk[i] = lo; tk[l] = hi;
          }
        }
    // lower-half of union + bitonic clean
    u64 m16[16];
    #pragma unroll
    for (int i = 0; i < 16; ++i){
      u64 a = list[i], bb = tk[15 - i];
      m16[i] = a < bb ? a : bb;
    }
    #pragma unroll
    for (int j2 = 8; j2 > 0; j2 >>= 1)
      #pragma unroll
      for (int i = 0; i < 16; ++i){
        int l = i ^ j2;
        if (l > i){
          u64 a = m16[i], bb = m16[l];
          bool sw = a > bb;
          m16[i] = sw ? bb : a; m16[l] = sw ? a : bb;
        }
      }
    #pragma unroll
    for (int i = 0; i < 16; ++i) list[i] = m16[i];
  }

  int q = b*N_ + n;
  #pragma unroll
  for (int j = 0; j < 16; ++j)
    kout[(size_t)(chunk*16 + j)*NQ + q] = list[j];
}

// ---------------------------------------------------------------------------
// FAT 2: blocks [0,64) = merge 16 sorted lists ; blocks [64,320) = p1_gemm.
// ---------------------------------------------------------------------------
__global__ __launch_bounds__(256) void merge_p1(
    const u64* __restrict__ kin, int* __restrict__ idxout,
    const float* __restrict__ feat2, const float* __restrict__ feat1,
    const unsigned short* __restrict__ W0b, const unsigned short* __restrict__ W0c,
    float* __restrict__ F2t, float* __restrict__ PREt)
{
  if (blockIdx.x < 64){
    int q = blockIdx.x*256 + threadIdx.x;
    u64 list[16];
    #pragma unroll
    for (int j = 0; j < 16; ++j) list[j] = ~0ull;
    #pragma unroll 1
    for (int l = 0; l < 16; ++l){
      u64 lv[16];
      #pragma unroll
      for (int j = 0; j < 16; ++j)
        lv[j] = kin[(size_t)(l*16 + j)*NQ + q];
      bool dead = false;
      #pragma unroll
      for (int j = 0; j < 16; ++j){
        bool ins = !dead && (list[15] > lv[j]);
        dead = !ins;
        if (__any(ins)){
          if (ins){
            u64 key = lv[j];
            bool cm = list[14] > key;
            list[15] = cm ? list[14] : key;
            #pragma unroll
            for (int jj = 14; jj >= 1; --jj){
              bool cj = cm;
              cm = list[jj-1] > key;
              list[jj] = cj ? (cm ? list[jj-1] : key) : list[jj];
            }
            list[0] = cm ? key : list[0];
          }
        }
      }
    }
    #pragma unroll
    for (int j = 0; j < 4; ++j){
      i4 v;
      v.x = (int)(list[j*4]   & 0xFFF); v.y = (int)(list[j*4+1] & 0xFFF);
      v.z = (int)(list[j*4+2] & 0xFFF); v.w = (int)(list[j*4+3] & 0xFFF);
      *(i4*)(idxout + (size_t)q*16 + j*4) = v;
    }
    return;
  }
  // ---- p1_gemm part ----
  __shared__ __align__(16) unsigned short X[16*128*8];  // 32KB
  int bid = blockIdx.x - 64;
  int sel = bid >> 7;
  const float* src = sel ? feat1 : feat2;
  const unsigned short* W = sel ? W0c : W0b;
  float* dst = sel ? PREt : F2t;
  int c0 = (bid & 127) * 128;
  int b = c0 >> 12, mm0 = c0 & 4095;
  int t = threadIdx.x;
  {
    int colt = t & 127, chh = t >> 7;
    #pragma unroll 4
    for (int it = 0; it < 64; ++it){
      int ch = it*2 + chh;
      float v = src[((size_t)b*C_ + ch)*N_ + mm0 + colt];
      X[(ch >> 3)*1024 + swzc(colt)*8 + (ch & 7)] = f2bf(v);
    }
  }
  int lane = t & 63, w = t >> 6;
  int or0 = (w >> 1)*64, c0w = (w & 1)*64;
  int lr = lane & 15, lg = lane >> 4;
  short8 af[4][4];
  #pragma unroll
  for (int ks = 0; ks < 4; ++ks)
    #pragma unroll
    for (int i = 0; i < 4; ++i)
      af[ks][i] = *(const short8*)(W + (or0 + 16*i + lr)*128 + ks*32 + 8*lg);
  __syncthreads();

  f4 acc[4][4] = {};
  #pragma unroll
  for (int ks = 0; ks < 4; ++ks){
    short8 bfr[4];
    #pragma unroll
    for (int j = 0; j < 4; ++j)
      bfr[j] = *(const short8*)(X + (ks*4 + lg)*1024 + swzc(c0w + 16*j + lr)*8);
    #pragma unroll
    for (int i = 0; i < 4; ++i)
      #pragma unroll
      for (int j = 0; j < 4; ++j)
        acc[i][j] = __builtin_amdgcn_mfma_f32_16x16x32_bf16(af[ks][i], bfr[j], acc[i][j], 0, 0, 0);
  }
  #pragma unroll
  for (int i = 0; i < 4; ++i)
    #pragma unroll
    for (int j = 0; j < 4; ++j){
      int col = c0 + c0w + 16*j + lr;
      *(f4*)(dst + (size_t)col*C_ + or0 + 16*i + 4*lg) = acc[i][j];
    }
}

// ---------------------------------------------------------------------------
// K3_STATS: per-channel sum/sumsq of y0 (arithmetic == verified k3)
// ---------------------------------------------------------------------------
__global__ __launch_bounds__(256) void k3_stats(
    const float* __restrict__ pos1, const float* __restrict__ pos2,
    const float* __restrict__ W0, const int* __restrict__ idx,
    const float* __restrict__ F2t, const float* __restrict__ PREt,
    float* __restrict__ partials)
{
  __shared__ float w0a[384];
  __shared__ float ldsS[256];
  int t = threadIdx.x;
  for (int i = t; i < 384; i += 256) w0a[i] = W0[(i/3)*259 + (i%3)];
  __syncthreads();
  int cloc = t & 15, chg = t >> 4, ch0 = chg*8;
  float wx[8], wy[8], wz[8];
  #pragma unroll
  for (int e = 0; e < 8; ++e){
    wx[e] = w0a[(ch0+e)*3]; wy[e] = w0a[(ch0+e)*3+1]; wz[e] = w0a[(ch0+e)*3+2];
  }
  float s1[8] = {}, s2[8] = {};
  int base = blockIdx.x * 256;
  for (int it = 0; it < 16; ++it){
    int col = base + it*16 + cloc;
    int nabs = col >> 4;
    int b = nabs >> 12, n = nabs & 4095;
    int m = idx[col];
    float dx = pos2[(size_t)(b*3+0)*N_ + m] - pos1[(size_t)(b*3+0)*N_ + n];
    float dy = pos2[(size_t)(b*3+1)*N_ + m] - pos1[(size_t)(b*3+1)*N_ + n];
    float dz = pos2[(size_t)(b*3+2)*N_ + m] - pos1[(size_t)(b*3+2)*N_ + n];
    const float* f2 = F2t  + ((size_t)b*N_ + m)*C_ + ch0;
    const float* pr = PREt + ((size_t)b*N_ + n)*C_ + ch0;
    #pragma unroll
    for (int e = 0; e < 8; ++e){
      float y = f2[e] + pr[e];
      y = fmaf(wx[e], dx, y); y = fmaf(wy[e], dy, y); y = fmaf(wz[e], dz, y);
      s1[e] += y; s2[e] = fmaf(y, y, s2[e]);
    }
  }
  #pragma unroll
  for (int e = 0; e < 8; ++e){
    float a = s1[e], q = s2[e];
    #pragma unroll
    for (int sft = 1; sft < 16; sft <<= 1){ a += __shfl_xor(a, sft); q += __shfl_xor(q, sft); }
    if (cloc == 0){ ldsS[ch0 + e] = a; ldsS[128 + ch0 + e] = q; }
  }
  __syncthreads();
  partials[(size_t)blockIdx.x*256 + t] = ldsS[t];
}

// ---------------------------------------------------------------------------
// REDFIN: reduce partials (32 rows/block) + last-block finalize (BN coefs).
// Deterministic: fixed sum orders; device-fence + counter; counter self-resets.
// ---------------------------------------------------------------------------
__global__ __launch_bounds__(256) void redfin(
    const float* __restrict__ partials, float* __restrict__ partial2,
    const float* __restrict__ g, const float* __restrict__ bb,
    float* __restrict__ cA, float* __restrict__ cB,
    int* __restrict__ counter)
{
  __shared__ float sh[256];
  __shared__ int isLast;
  int t = threadIdx.x, blk = blockIdx.x, R = gridDim.x;
  float a = 0.f;
  int r0 = blk*32;
  #pragma unroll 4
  for (int i = 0; i < 32; ++i) a += partials[(size_t)(r0+i)*256 + t];
  partial2[(size_t)blk*256 + t] = a;
  __threadfence();
  if (t == 0){
    int old = atomicAdd(counter, 1);
    isLast = (old == R - 1);
  }
  __syncthreads();
  if (!isLast) return;
  __threadfence();
  float s = 0.f;
  for (int i = 0; i < R; ++i) s += partial2[(size_t)i*256 + t];
  sh[t] = s;
  __syncthreads();
  if (t < 128){
    float mu = sh[t] / CNT_F;
    float var = sh[128 + t] / CNT_F - mu*mu;
    float A = g[t] * rsqrtf(var + EPS_);
    cA[t] = A; cB[t] = bb[t] - mu*A;
  }
  if (t == 0) *counter = 0;
}

// ---------------------------------------------------------------------------
// LAYER1 FUSED: recompute y0, BN0+relu -> X, MFMA W1, stats, write y1 bf16.
// ---------------------------------------------------------------------------
__global__ __launch_bounds__(256,2) void layer1_fused(
    const float* __restrict__ pos1, const float* __restrict__ pos2,
    const float* __restrict__ W0, const int* __restrict__ idx,
    const float* __restrict__ F2t, const float* __restrict__ PREt,
    unsigned short* __restrict__ ybuf,
    const unsigned short* __restrict__ Wbf,
    const float* __restrict__ cA, const float* __restrict__ cB,
    float* __restrict__ partials)
{
  __shared__ __align__(16) char lds[40960];
  unsigned short* X = (unsigned short*)lds;            // 32KB
  float* ldsA = (float*)(lds + 32768);
  float* ldsB = ldsA + 128;
  float* w0a  = ldsB + 128;
  float* ldsS = w0a + 384;
  int t = threadIdx.x;
  int c0 = blockIdx.x * 128;
  if (t < 128){ ldsA[t] = cA[t]; ldsB[t] = cB[t]; }
  for (int i = t; i < 384; i += 256) w0a[i] = W0[(i/3)*259 + (i%3)];
  ldsS[t] = 0.f; ldsS[256 + t] = 0.f;
  __syncthreads();

  int lane = t & 63, w = t >> 6;
  int or0 = (w >> 1)*64, c0w = (w & 1)*64;
  int lr = lane & 15, lg = lane >> 4;

  {
    int colL = t >> 1, half = t & 1;
    int col = c0 + colL;
    int nabs = col >> 4;
    int b = nabs >> 12, n = nabs & 4095;
    int m = idx[col];
    float dx = pos2[(size_t)(b*3+0)*N_ + m] - pos1[(size_t)(b*3+0)*N_ + n];
    float dy = pos2[(size_t)(b*3+1)*N_ + m] - pos1[(size_t)(b*3+1)*N_ + n];
    float dz = pos2[(size_t)(b*3+2)*N_ + m] - pos1[(size_t)(b*3+2)*N_ + n];
    const float* f2 = F2t  + ((size_t)b*N_ + m)*C_ + half*64;
    const float* pr = PREt + ((size_t)b*N_ + n)*C_ + half*64;
    int sc = swzc(colL);
    #pragma unroll
    for (int cc = 0; cc < 8; ++cc){
      int ch0 = half*64 + cc*8;
      f4 a0 = *(const f4*)(f2 + cc*8), a1 = *(const f4*)(f2 + cc*8 + 4);
      f4 b0 = *(const f4*)(pr + cc*8), b1 = *(const f4*)(pr + cc*8 + 4);
      short8 xv;
      #pragma unroll
      for (int e = 0; e < 8; ++e){
        int ch = ch0 + e;
        float fv = (e < 4 ? a0[e] : a1[e-4]);
        float pv = (e < 4 ? b0[e] : b1[e-4]);
        float y = fv + pv;
        y = fmaf(w0a[ch*3], dx, y); y = fmaf(w0a[ch*3+1], dy, y); y = fmaf(w0a[ch*3+2], dz, y);
        float v = fmaf(y, ldsA[ch], ldsB[ch]);
        v = v > 0.f ? v : 0.f;
        xv[e] = (short)f2bf(v);
      }
      *(short8*)(X + (ch0 >> 3)*1024 + sc*8) = xv;
    }
  }

  short8 af[4][4];
  #pragma unroll
  for (int ks = 0; ks < 4; ++ks)
    #pragma unroll
    for (int i = 0; i < 4; ++i)
      af[ks][i] = *(const short8*)(Wbf + (or0 + 16*i + lr)*128 + ks*32 + 8*lg);
  __syncthreads();

  f4 acc[4][4] = {};
  #pragma unroll
  for (int ks = 0; ks < 4; ++ks){
    short8 bfr[4];
    #pragma unroll
    for (int j = 0; j < 4; ++j)
      bfr[j] = *(const short8*)(X + (ks*4 + lg)*1024 + swzc(c0w + 16*j + lr)*8);
    #pragma unroll
    for (int i = 0; i < 4; ++i)
      #pragma unroll
      for (int j = 0; j < 4; ++j)
        acc[i][j] = __builtin_amdgcn_mfma_f32_16x16x32_bf16(af[ks][i], bfr[j], acc[i][j], 0, 0, 0);
  }

  #pragma unroll
  for (int i = 0; i < 4; ++i)
    #pragma unroll
    for (int e = 0; e < 4; ++e){
      float a0 = acc[i][0][e], a1 = acc[i][1][e], a2 = acc[i][2][e], a3 = acc[i][3][e];
      float s1 = (a0 + a1) + (a2 + a3);
      float s2 = (a0*a0 + a1*a1) + (a2*a2 + a3*a3);
      #pragma unroll
      for (int sft = 1; sft < 16; sft <<= 1){ s1 += __shfl_xor(s1, sft); s2 += __shfl_xor(s2, sft); }
      if (lr == 0){
        int o = or0 + 16*i + 4*lg + e;
        ldsS[(w & 1)*256 + o] = s1;
        ldsS[(w & 1)*256 + 128 + o] = s2;
      }
    }

  __syncthreads();
  unsigned short* OT = (unsigned short*)lds;
  #pragma unroll
  for (int i = 0; i < 4; ++i)
    #pragma unroll
    for (int j = 0; j < 4; ++j){
      int col = c0w + 16*j + lr;
      int o0 = or0 + 16*i + 4*lg;
      unsigned long long pv =
          (unsigned long long)f2bf(acc[i][j][0])
        | ((unsigned long long)f2bf(acc[i][j][1]) << 16)
        | ((unsigned long long)f2bf(acc[i][j][2]) << 32)
        | ((unsigned long long)f2bf(acc[i][j][3]) << 48);
      *(unsigned long long*)(OT + col*136 + o0) = pv;
    }
  __syncthreads();
  {
    int colL = t >> 1, half = t & 1;
    unsigned short* dst = ybuf + (size_t)(c0 + colL)*128 + half*64;
    #pragma unroll
    for (int cc = 0; cc < 8; ++cc){
      short8 v = *(const short8*)(OT + colL*136 + half*64 + cc*8);
      *(short8*)(dst + cc*8) = v;
    }
  }
  __syncthreads();
  partials[(size_t)blockIdx.x*256 + t] = ldsS[t] + ldsS[256 + t];
}

// ---------------------------------------------------------------------------
// Layer GEMM (LAST): x = relu(A*y1+B), y2 = W2 @ x, in-reg K-max.
// ---------------------------------------------------------------------------
__global__ __launch_bounds__(256,2) void layer_gemm_last(
    unsigned short* ybuf,
    const unsigned short* __restrict__ Wbf,
    const float* __restrict__ cA, const float* __restrict__ cB,
    float* __restrict__ y2max,
    float* __restrict__ partials)
{
  __shared__ __align__(16) char lds[38912];
  unsigned short* X = (unsigned short*)lds;
  float* ldsA = (float*)(lds + 34816);
  float* ldsB = ldsA + 128;
  float* ldsS = ldsB + 128;
  int t = threadIdx.x;
  int c0 = blockIdx.x * 128;
  if (t < 128){ ldsA[t] = cA[t]; ldsB[t] = cB[t]; }
  ldsS[t] = 0.f; ldsS[256 + t] = 0.f;

  int lane = t & 63, w = t >> 6;
  int or0 = (w >> 1)*64, c0w = (w & 1)*64;
  int lr = lane & 15, lg = lane >> 4;
  short8 af[4][4];
  #pragma unroll
  for (int ks = 0; ks < 4; ++ks)
    #pragma unroll
    for (int i = 0; i < 4; ++i)
      af[ks][i] = *(const short8*)(Wbf + (or0 + 16*i + lr)*128 + ks*32 + 8*lg);
  __syncthreads();

  {
    int colL = t >> 1, half = t & 1;
    const unsigned short* src = ybuf + (size_t)(c0 + colL)*128 + half*64;
    int sc = swzc(colL);
    #pragma unroll
    for (int cc = 0; cc < 8; ++cc){
      int ch0 = half*64 + cc*8;
      short8 yv = *(const short8*)(src + cc*8);
      short8 xv;
      #pragma unroll
      for (int e = 0; e < 8; ++e){
        float f = bf2f((unsigned short)yv[e]);
        float v = fmaf(f, ldsA[ch0 + e], ldsB[ch0 + e]);
        v = v > 0.f ? v : 0.f;
        xv[e] = (short)f2bf(v);
      }
      *(short8*)(X + (ch0 >> 3)*1024 + sc*8) = xv;
    }
  }
  __syncthreads();

  f4 acc[4][4] = {};
  #pragma unroll
  for (int ks = 0; ks < 4; ++ks){
    short8 bfr[4];
    #pragma unroll
    for (int j = 0; j < 4; ++j)
      bfr[j] = *(const short8*)(X + (ks*4 + lg)*1024 + swzc(c0w + 16*j + lr)*8);
    #pragma unroll
    for (int i = 0; i < 4; ++i)
      #pragma unroll
      for (int j = 0; j < 4; ++j)
        acc[i][j] = __builtin_amdgcn_mfma_f32_16x16x32_bf16(af[ks][i], bfr[j], acc[i][j], 0, 0, 0);
  }

  #pragma unroll
  for (int i = 0; i < 4; ++i)
    #pragma unroll
    for (int e = 0; e < 4; ++e){
      float a0 = acc[i][0][e], a1 = acc[i][1][e], a2 = acc[i][2][e], a3 = acc[i][3][e];
      float s1 = (a0 + a1) + (a2 + a3);
      float s2 = (a0*a0 + a1*a1) + (a2*a2 + a3*a3);
      #pragma unroll
      for (int sft = 1; sft < 16; sft <<= 1){ s1 += __shfl_xor(s1, sft); s2 += __shfl_xor(s2, sft); }
      if (lr == 0){
        int o = or0 + 16*i + 4*lg + e;
        ldsS[(w & 1)*256 + o] = s1;
        ldsS[(w & 1)*256 + 128 + o] = s2;
      }
    }

  float keep[4][4] = {};
  #pragma unroll
  for (int j = 0; j < 4; ++j)
    #pragma unroll
    for (int i = 0; i < 4; ++i)
      #pragma unroll
      for (int e = 0; e < 4; ++e){
        float v = acc[i][j][e];
        #pragma unroll
        for (int sft = 1; sft < 16; sft <<= 1) v = fmaxf(v, __shfl_xor(v, sft));
        if (lr == j) keep[i][e] = v;
      }
  if (lr < 4){
    int colg = c0 + c0w + 16*lr;
    int nabs = colg >> 4;
    float* dst = y2max + (size_t)nabs*C_;
    #pragma unroll
    for (int i = 0; i < 4; ++i){
      f4 v; v.x = keep[i][0]; v.y = keep[i][1]; v.z = keep[i][2]; v.w = keep[i][3];
      *(f4*)(dst + or0 + 16*i + 4*lg) = v;
    }
  }
  __syncthreads();
  partials[(size_t)blockIdx.x*256 + t] = ldsS[t] + ldsS[256 + t];
}

// ---------------------------------------------------------------------------
// FAT 3: blocks [0,256) = K7 (BN2+relu transpose out) ; [256,304) = pos1 copy.
// ---------------------------------------------------------------------------
__global__ __launch_bounds__(256) void k7_fat(
    const float* __restrict__ y2max, const float* __restrict__ cA,
    const float* __restrict__ cB, float* __restrict__ outF,
    const float* __restrict__ pos1, float* __restrict__ out0)
{
  if (blockIdx.x >= 256){
    int i = ((blockIdx.x - 256)*256 + threadIdx.x)*4;   // 48 blocks x 1024 floats
    *(f4*)(out0 + i) = *(const f4*)(pos1 + i);
    return;
  }
  __shared__ __align__(16) float T[128*65];
  int t = threadIdx.x, bid = blockIdx.x;
  int b = bid >> 6, n0 = (bid & 63)*64;
  {
    int nl = t >> 2, o0 = (t & 3)*32;
    const float* src = y2max + ((size_t)b*N_ + n0 + nl)*C_ + o0;
    #pragma unroll
    for (int jj = 0; jj < 8; ++jj){
      f4 v = *(const f4*)(src + jj*4);
      T[(o0 + jj*4 + 0)*65 + nl] = v.x;
      T[(o0 + jj*4 + 1)*65 + nl] = v.y;
      T[(o0 + jj*4 + 2)*65 + nl] = v.z;
      T[(o0 + jj*4 + 3)*65 + nl] = v.w;
    }
  }
  __syncthreads();
  {
    int o = t >> 1, half = t & 1;
    float A = cA[o], Bb = cB[o];
    float* dst = outF + ((size_t)b*C_ + o)*N_ + n0 + half*32;
    #pragma unroll
    for (int jj = 0; jj < 8; ++jj){
      f4 v;
      float x0 = fmaf(T[o*65 + half*32 + jj*4+0], A, Bb);
      float x1 = fmaf(T[o*65 + half*32 + jj*4+1], A, Bb);
      float x2 = fmaf(T[o*65 + half*32 + jj*4+2], A, Bb);
      float x3 = fmaf(T[o*65 + half*32 + jj*4+3], A, Bb);
      v.x = x0 > 0.f ? x0 : 0.f; v.y = x1 > 0.f ? x1 : 0.f;
      v.z = x2 > 0.f ? x2 : 0.f; v.w = x3 > 0.f ? x3 : 0.f;
      *(f4*)(dst + jj*4) = v;
    }
  }
}

// ---------------------------------------------------------------------------
extern "C" void kernel_launch(void* const* d_in, const int* in_sizes, int n_in,
                              void* d_out, int out_size, void* d_ws, size_t ws_size,
                              hipStream_t stream)
{
  (void)in_sizes; (void)n_in; (void)out_size; (void)ws_size;
  const float* pos1  = (const float*)d_in[0];
  const float* pos2  = (const float*)d_in[1];
  const float* feat1 = (const float*)d_in[2];
  const float* feat2 = (const float*)d_in[3];
  const float* W0 = (const float*)d_in[4];
  const float* W1 = (const float*)d_in[5];
  const float* W2 = (const float*)d_in[6];
  const float* g0 = (const float*)d_in[7];
  const float* g1 = (const float*)d_in[8];
  const float* g2 = (const float*)d_in[9];
  const float* b0 = (const float*)d_in[10];
  const float* b1 = (const float*)d_in[11];
  const float* b2 = (const float*)d_in[12];

  char* ws = (char*)d_ws;
  size_t off = 0;
  auto alloc = [&](size_t bytes){ size_t r = off; off += (bytes + 255) & ~(size_t)255; return r; };
  int*   idx     = (int*)  (ws + alloc((size_t)COLS_TOT*4));       // 1 MB
  float* F2t     = (float*)(ws + alloc((size_t)NQ*C_*4));          // 8 MB
  float* PREt    = (float*)(ws + alloc((size_t)NQ*C_*4));          // 8 MB
  unsigned short* ybuf = (unsigned short*)(ws + alloc((size_t)COLS_TOT*C_*2)); // 64 MiB
  float* y2max   = (float*)(ws + alloc((size_t)NQ*C_*4));          // 8 MB
  float* partials= (float*)(ws + alloc((size_t)2048*256*4));       // 2 MB
  float* partial2= (float*)(ws + alloc((size_t)64*256*4));
  float* coef    = (float*)(ws + alloc((size_t)6*128*4));
  int*   ctrs    = (int*)  (ws + alloc(256));
  unsigned short* W0bb = (unsigned short*)(ws + alloc(16384*2));
  unsigned short* W0cb = (unsigned short*)(ws + alloc(16384*2));
  unsigned short* W1b  = (unsigned short*)(ws + alloc(16384*2));
  unsigned short* W2b  = (unsigned short*)(ws + alloc(16384*2));

  // KNN scratch ALIASES ybuf (33.5 MB < 64 MiB; consumed before ybuf written)
  u64* knn_k = (u64*)ybuf;

  float* cA0 = coef,       *cB0 = coef + 128;
  float* cA1 = coef + 256, *cB1 = coef + 384;
  float* cA2 = coef + 512, *cB2 = coef + 640;

  hipMemsetAsync(ctrs, 0, 256, stream);
  knn_wconv<<<1280, 256, 0, stream>>>(pos1, pos2, knn_k, W0, W1, W2,
                                       W0bb, W0cb, W1b, W2b);
  merge_p1<<<320, 256, 0, stream>>>(knn_k, idx, feat2, feat1, W0bb, W0cb, F2t, PREt);
  k3_stats<<<1024, 256, 0, stream>>>(pos1, pos2, W0, idx, F2t, PREt, partials);
  redfin<<<32, 256, 0, stream>>>(partials, partial2, g0, b0, cA0, cB0, ctrs + 0);
  layer1_fused<<<2048, 256, 0, stream>>>(pos1, pos2, W0, idx, F2t, PREt,
                                          ybuf, W1b, cA0, cB0, partials);
  redfin<<<64, 256, 0, stream>>>(partials, partial2, g1, b1, cA1, cB1, ctrs + 16);
  layer_gemm_last<<<2048, 256, 0, stream>>>(ybuf, W2b, cA1, cB1, y2max, partials);
  redfin<<<64, 256, 0, stream>>>(partials, partial2, g2, b2, cA2, cB2, ctrs + 32);
  k7_fat<<<304, 256, 0, stream>>>(y2max, cA2, cB2,
                                   (float*)d_out + (size_t)B_*3*N_, pos1, (float*)d_out);
}